// Round 2
// baseline (716.497 us; speedup 1.0000x reference)
//
#include <hip/hip_runtime.h>
#include <hip/hip_bf16.h>
#include <cstdint>

// GAT 3-layer pipeline, MI355X. B=4, N=2048, Fin=128, nhid=64, H=8, emb=64, nclass=16.
// All float tensors are fp32 (round-1 NaN signature falsified the bf16 hypothesis).
// d_out = [image_feature (4*2048*64) | pre (4*16)] fp32.

#define NN 2048

// ---------------- adj -> bitmask (2048 rows x 32 uint64 words) ----------------
__global__ __launch_bounds__(256) void build_mask_k(const int* __restrict__ adj,
                                                    unsigned long long* __restrict__ mb) {
  const int row = blockIdx.x;
  const int t = threadIdx.x;
  const int wave = t >> 6;
  const int lane = t & 63;
#pragma unroll
  for (int iter = 0; iter < NN / 256; ++iter) {
    const int j = iter * 256 + t;
    const int v = adj[(size_t)row * NN + j];
    const unsigned long long m = __ballot(v > 0);
    if (lane == 0) mb[(size_t)row * 32 + iter * 4 + wave] = m;
  }
}

// ---------------- GEMM: C[p] = A[b] @ B[h], Ncols=64, 32-row tiles ----------------
// p = blockIdx.y, b = p&3, h = p>>2.
__global__ __launch_bounds__(256) void gemm64_k(const float* __restrict__ Aall,
                                                const float* __restrict__ Ball,
                                                float* __restrict__ Call,
                                                int K, long aStrideB, long bStrideH,
                                                long cStrideP) {
  const int p = blockIdx.y;
  const int bb = p & 3, hh = p >> 2;
  const float* A = Aall + (long)bb * aStrideB;
  const float* Bw = Ball + (long)hh * bStrideH;
  float* C = Call + (long)p * cStrideP;
  const int r0 = blockIdx.x * 32;
  const int t = threadIdx.x;
  __shared__ float As[32][33];
  __shared__ float Bs[32][64];
  const int cg = t & 15, rb = t >> 4;  // cols cg*4..+3, rows rb and rb+16
  float acc0[4] = {0.f, 0.f, 0.f, 0.f};
  float acc1[4] = {0.f, 0.f, 0.f, 0.f};
  for (int k0 = 0; k0 < K; k0 += 32) {
#pragma unroll
    for (int q = 0; q < 4; ++q) {  // stage A 32x32
      const int idx = q * 256 + t;
      const int tr = idx >> 5, tk = idx & 31;
      As[tr][tk] = A[(long)(r0 + tr) * K + (k0 + tk)];
    }
#pragma unroll
    for (int q = 0; q < 8; ++q) {  // stage B 32x64
      const int idx = q * 256 + t;
      const int kr = idx >> 6, c = idx & 63;
      Bs[kr][c] = Bw[(long)(k0 + kr) * 64 + c];
    }
    __syncthreads();
#pragma unroll 8
    for (int k = 0; k < 32; ++k) {
      const float a0 = As[rb][k];
      const float a1 = As[rb + 16][k];
      const float4 bv = *(const float4*)&Bs[k][cg * 4];
      acc0[0] += a0 * bv.x; acc0[1] += a0 * bv.y;
      acc0[2] += a0 * bv.z; acc0[3] += a0 * bv.w;
      acc1[0] += a1 * bv.x; acc1[1] += a1 * bv.y;
      acc1[2] += a1 * bv.z; acc1[3] += a1 * bv.w;
    }
    __syncthreads();
  }
  float* c0 = C + (long)(r0 + rb) * 64 + cg * 4;
  float* c1 = C + (long)(r0 + rb + 16) * 64 + cg * 4;
#pragma unroll
  for (int q = 0; q < 4; ++q) { c0[q] = acc0[q]; c1[q] = acc1[q]; }
}

// ---------------- esrc/edst: per-row dot(Wh_row, a_lo/a_hi) ----------------
__global__ __launch_bounds__(256) void ee_k(const float* __restrict__ WhAll,
                                            const float* __restrict__ aAll,
                                            float* __restrict__ esrc,
                                            float* __restrict__ edst,
                                            long whStride, long aStrideH) {
  const int p = blockIdx.y;
  const int hh = p >> 2;
  const float* row = WhAll + (long)p * whStride + (long)(blockIdx.x * 256 + threadIdx.x) * 64;
  const float* av = aAll + (long)hh * aStrideH;
  float s0 = 0.f, s1 = 0.f;
#pragma unroll 16
  for (int f = 0; f < 64; ++f) {
    const float w = row[f];
    s0 += w * av[f];
    s1 += w * av[64 + f];
  }
  const long n = (long)p * NN + blockIdx.x * 256 + threadIdx.x;
  esrc[n] = s0;
  edst[n] = s1;
}

// ---------------- fused masked-softmax + P@Wh, 32 rows per block ----------------
// out = elu( softmax_row(mask? lrelu(esrc_i+edst_j) : -inf) @ Wh ).
// Unnormalized accumulation; divide by row-sum at the end (exp(e-m) <= 1, sum <= 2048).
__global__ __launch_bounds__(256) void attn_pv_k(const float* __restrict__ WhAll,
                                                 const float* __restrict__ esrcAll,
                                                 const float* __restrict__ edstAll,
                                                 const unsigned int* __restrict__ mb,
                                                 float* __restrict__ outF,
                                                 float* __restrict__ outB,
                                                 long whBatch, int rowStride,
                                                 long strideB, long strideH) {
  const int p = blockIdx.y;
  const int bb = p & 3, hh = p >> 2;
  const float* Wh = WhAll + (long)p * whBatch;
  const float* esrc = esrcAll + (long)p * NN;
  const float* edst = edstAll + (long)p * NN;
  const long outOff = (long)bb * strideB + (long)hh * strideH;
  const int i0 = blockIdx.x * 32;
  const int t = threadIdx.x;

  __shared__ float whs[128][64];     // 32 KB: V tile
  __shared__ float ptile[32][129];   // 16.1 KB: probs tile (stride 129 -> conflict-free reads)
  __shared__ float redm[32][9];
  __shared__ float mrow[32];
  __shared__ float linv[32];

  // ---- phase 1: per-row masked max of lrelu(esrc_i + edst_j) ----
  {
    const int i = t & 31, g = t >> 5;
    const float es = esrc[i0 + i];
    const unsigned int* bits = mb + (long)(i0 + i) * 64;
    float lmax = -3.0e38f;
    for (int jb = g * 256; jb < g * 256 + 256; jb += 32) {
      const unsigned int w = bits[jb >> 5];
#pragma unroll
      for (int q = 0; q < 32; ++q) {
        float e = es + edst[jb + q];
        e = e >= 0.f ? e : 0.2f * e;
        lmax = ((w >> q) & 1u) ? fmaxf(lmax, e) : lmax;
      }
    }
    redm[i][g] = lmax;
  }
  __syncthreads();
  if (t < 32) {
    float m = redm[t][0];
#pragma unroll
    for (int g = 1; g < 8; ++g) m = fmaxf(m, redm[t][g]);
    mrow[t] = m;
  }
  __syncthreads();

  // p-compute assignment: row pi = t>>3, 16 consecutive j per thread
  const int pi = t >> 3;
  const int fj0 = (t & 7) * 16;
  const float pm = mrow[pi];
  const float pes = esrc[i0 + pi];
  const unsigned int* pbits = mb + (long)(i0 + pi) * 64;
  // FMA assignment: row fi = t&31, cols f0..f0+7
  const int fi = t & 31;
  const int f0 = (t >> 5) * 8;

  float lsum = 0.f;
  float acc[8] = {0.f, 0.f, 0.f, 0.f, 0.f, 0.f, 0.f, 0.f};

  for (int jt = 0; jt < NN / 128; ++jt) {
    const int jbase = jt * 128;
    // stage whs (coalesced float4)
    {
      const float4* src = (const float4*)(Wh + (long)jbase * 64);
      float4* dst = (float4*)(&whs[0][0]);
#pragma unroll
      for (int q = 0; q < 8; ++q) {
        const int idx = q * 256 + t;
        dst[idx] = src[idx];
      }
    }
    // compute ptile + accumulate row-sum
    {
      unsigned int w = pbits[(jbase + fj0) >> 5] >> ((jbase + fj0) & 31);
      float ls = 0.f;
#pragma unroll
      for (int q = 0; q < 16; ++q) {
        float e = pes + edst[jbase + fj0 + q];
        e = e >= 0.f ? e : 0.2f * e;
        const float pv = ((w >> q) & 1u) ? __expf(e - pm) : 0.f;
        ptile[pi][fj0 + q] = pv;
        ls += pv;
      }
      lsum += ls;
    }
    __syncthreads();
    // P @ V over this tile
#pragma unroll 8
    for (int j = 0; j < 128; ++j) {
      const float pv = ptile[fi][j];
      const float4 w0 = *(const float4*)&whs[j][f0];
      const float4 w1 = *(const float4*)&whs[j][f0 + 4];
      acc[0] += pv * w0.x; acc[1] += pv * w0.y;
      acc[2] += pv * w0.z; acc[3] += pv * w0.w;
      acc[4] += pv * w1.x; acc[5] += pv * w1.y;
      acc[6] += pv * w1.z; acc[7] += pv * w1.w;
    }
    __syncthreads();
  }

  // reduce row-sums (8 partials per row), then epilogue
  redm[pi][t & 7] = lsum;
  __syncthreads();
  if (t < 32) {
    float s = redm[t][0];
#pragma unroll
    for (int g = 1; g < 8; ++g) s += redm[t][g];
    linv[t] = s > 0.f ? 1.0f / s : 0.f;  // guard fully-masked row (avoid 0*inf = NaN)
  }
  __syncthreads();
  {
    const float il = linv[fi];
    float* orow = outF + outOff + (long)(i0 + fi) * rowStride + f0;
    float* brow = outB ? outB + outOff + (long)(i0 + fi) * rowStride + f0 : (float*)nullptr;
#pragma unroll
    for (int q = 0; q < 8; ++q) {
      float v = acc[q] * il;
      v = v > 0.f ? v : expm1f(v);  // elu
      orow[q] = v;
      if (brow) brow[q] = v;
    }
  }
}

// ---------------- layer-3 Wh3 = imgfeat @ W2 (K=64, Nc=16) ----------------
__global__ __launch_bounds__(256) void gemm16_k(const float* __restrict__ Aall,
                                                const float* __restrict__ Bw,
                                                float* __restrict__ Call) {
  const int bb = blockIdx.y;
  const float* A = Aall + (long)bb * NN * 64;
  float* C = Call + (long)bb * NN * 16;
  const int r0 = blockIdx.x * 16;
  const int t = threadIdx.x;
  __shared__ float As[16][65];
  __shared__ float Bs[64][16];
  const int c = t & 15, r = t >> 4;
#pragma unroll
  for (int q = 0; q < 4; ++q) {
    const int idx = q * 256 + t;
    As[idx >> 6][idx & 63] = A[(long)(r0 + (idx >> 6)) * 64 + (idx & 63)];
    Bs[idx >> 4][idx & 15] = Bw[idx];
  }
  __syncthreads();
  float acc = 0.f;
#pragma unroll 16
  for (int k = 0; k < 64; ++k) acc += As[r][k] * Bs[k][c];
  C[(long)(r0 + r) * 16 + c] = acc;
}

// ---------------- layer-3 finalize: only row 0 of attention is needed ----------------
__global__ __launch_bounds__(256) void layer3_k(const float* __restrict__ Wh3,
                                                const float* __restrict__ a2,
                                                const unsigned int* __restrict__ mb,
                                                float* __restrict__ outPre) {
  const int bb = blockIdx.x, t = threadIdx.x;
  const float* W = Wh3 + (long)bb * NN * 16;
  __shared__ float wmax[4];
  __shared__ float mfin;
  __shared__ float wsum[4];
  __shared__ float vacc[4][16];
  float alo[16], ahi[16];
#pragma unroll
  for (int c = 0; c < 16; ++c) { alo[c] = a2[c]; ahi[c] = a2[16 + c]; }
  float es = 0.f;
#pragma unroll
  for (int c = 0; c < 16; ++c) es += W[c] * alo[c];

  float ereg[NN / 256];
  float lmax = -3.0e38f;
  int qi = 0;
  for (int j = t; j < NN; j += 256, ++qi) {
    float ed = 0.f;
#pragma unroll
    for (int c = 0; c < 16; ++c) ed += W[(long)j * 16 + c] * ahi[c];
    float e = es + ed;
    e = e >= 0.f ? e : 0.2f * e;
    const bool ok = (mb[j >> 5] >> (j & 31)) & 1u;
    ereg[qi] = ok ? e : -3.0e38f;
    if (ok) lmax = fmaxf(lmax, e);
  }
#pragma unroll
  for (int off = 32; off > 0; off >>= 1) lmax = fmaxf(lmax, __shfl_down(lmax, off));
  if ((t & 63) == 0) wmax[t >> 6] = lmax;
  __syncthreads();
  if (t == 0) mfin = fmaxf(fmaxf(wmax[0], wmax[1]), fmaxf(wmax[2], wmax[3]));
  __syncthreads();
  const float m = mfin;

  float lsum = 0.f;
  float acc[16];
#pragma unroll
  for (int c = 0; c < 16; ++c) acc[c] = 0.f;
  qi = 0;
  for (int j = t; j < NN; j += 256, ++qi) {
    const float pv = __expf(ereg[qi] - m);  // masked -> exp(-huge) = 0
    lsum += pv;
#pragma unroll
    for (int c = 0; c < 16; ++c) acc[c] += pv * W[(long)j * 16 + c];
  }
#pragma unroll
  for (int off = 32; off > 0; off >>= 1) {
    lsum += __shfl_down(lsum, off);
#pragma unroll
    for (int c = 0; c < 16; ++c) acc[c] += __shfl_down(acc[c], off);
  }
  if ((t & 63) == 0) {
    wsum[t >> 6] = lsum;
#pragma unroll
    for (int c = 0; c < 16; ++c) vacc[t >> 6][c] = acc[c];
  }
  __syncthreads();
  if (t < 16) {
    const float a = vacc[0][t] + vacc[1][t] + vacc[2][t] + vacc[3][t];
    const float l = wsum[0] + wsum[1] + wsum[2] + wsum[3];
    float v = a / l;
    v = v > 0.f ? v : expm1f(v);
    outPre[bb * 16 + t] = v;
  }
}

// ---------------- host ----------------
extern "C" void kernel_launch(void* const* d_in, const int* in_sizes, int n_in,
                              void* d_out, int out_size, void* d_ws, size_t ws_size,
                              hipStream_t stream) {
  (void)in_sizes; (void)n_in; (void)out_size; (void)ws_size;
  constexpr int B = 4, N = NN, FIN = 128, NHID = 64, H = 8;

  const float* slices = (const float*)d_in[0];
  const int* adj = (const int*)d_in[1];
  const float* Ws = (const float*)d_in[2];
  const float* As = (const float*)d_in[3];
  const float* W1 = (const float*)d_in[4];
  const float* a1 = (const float*)d_in[5];
  const float* W2 = (const float*)d_in[6];
  const float* a2 = (const float*)d_in[7];
  float* out = (float*)d_out;

  char* w = (char*)d_ws;
  size_t off = 0;
  auto alloc = [&](size_t bytes) {
    void* p = w + off;
    off += (bytes + 255) & ~(size_t)255;
    return p;
  };
  unsigned long long* mb = (unsigned long long*)alloc((size_t)N * 32 * 8);   // 512 KB
  float* Wh1   = (float*)alloc((size_t)H * B * N * NHID * 4);                // 16 MB
  float* esrc1 = (float*)alloc((size_t)H * B * N * 4);
  float* edst1 = (float*)alloc((size_t)H * B * N * 4);
  float* x     = (float*)alloc((size_t)B * N * H * NHID * 4);                // 16 MB
  float* Wh2   = (float*)alloc((size_t)B * N * NHID * 4);                    // 2 MB
  float* esrc2 = (float*)alloc((size_t)B * N * 4);
  float* edst2 = (float*)alloc((size_t)B * N * 4);
  float* img   = (float*)alloc((size_t)B * N * NHID * 4);                    // 2 MB
  float* Wh3   = (float*)alloc((size_t)B * N * 16 * 4);                      // 512 KB

  const unsigned int* mb32 = (const unsigned int*)mb;

  build_mask_k<<<dim3(N), dim3(256), 0, stream>>>(adj, mb);

  // layer 1: Wh1[h*4+b] = slices[b] @ Ws[h]
  gemm64_k<<<dim3(N / 32, H * B), dim3(256), 0, stream>>>(
      slices, Ws, Wh1, FIN, (long)N * FIN, (long)FIN * NHID, (long)N * NHID);
  ee_k<<<dim3(N / 256, H * B), dim3(256), 0, stream>>>(
      Wh1, As, esrc1, edst1, (long)N * NHID, (long)2 * NHID);
  // x[b][n][h*64+f] = elu(att @ Wh1)
  attn_pv_k<<<dim3(N / 32, H * B), dim3(256), 0, stream>>>(
      Wh1, esrc1, edst1, mb32, x, (float*)nullptr,
      (long)N * NHID, H * NHID, (long)N * H * NHID, (long)NHID);

  // layer 2: Wh2[b] = x[b] @ W1; img = elu(att @ Wh2); also write image_feature to out
  gemm64_k<<<dim3(N / 32, B), dim3(256), 0, stream>>>(
      x, W1, Wh2, H * NHID, (long)N * H * NHID, 0L, (long)N * NHID);
  ee_k<<<dim3(N / 256, B), dim3(256), 0, stream>>>(
      Wh2, a1, esrc2, edst2, (long)N * NHID, 0L);
  attn_pv_k<<<dim3(N / 32, B), dim3(256), 0, stream>>>(
      Wh2, esrc2, edst2, mb32, img, out,
      (long)N * NHID, NHID, (long)N * NHID, 0L);

  // layer 3: only attention row 0 matters for pre[:,0,:]
  gemm16_k<<<dim3(N / 16, B), dim3(256), 0, stream>>>(img, W2, Wh3);
  layer3_k<<<dim3(B), dim3(256), 0, stream>>>(Wh3, a2, mb32, out + (size_t)B * N * NHID);
}

// Round 3
// 347.073 us; speedup vs baseline: 2.0644x; 2.0644x over previous
//
#include <hip/hip_runtime.h>
#include <hip/hip_bf16.h>
#include <cstdint>

// GAT 3-layer pipeline, MI355X. B=4, N=2048, Fin=128, nhid=64, H=8, emb=64, nclass=16.
// fp32 tensors; d_out = [image_feature (4*2048*64) | pre (4*16)] fp32.
// Round 3: attention P@V via bf16 MFMA (16x16x32), P generated in A-frag layout in
// registers, Wh pre-swizzled to B-frag order (bf16) in the gemm64 epilogue.
// Safe-softmax bound m_i = lrelu(esrc_i + max_j edst_j) (lrelu monotone) kills the max pass.

#define NN 2048

typedef float f32x4 __attribute__((ext_vector_type(4)));
typedef __bf16 bf16x8 __attribute__((ext_vector_type(8)));

__device__ __forceinline__ float lrelu(float x) { return fmaxf(x, 0.2f * x); }

// ---------------- adj -> bitmask (2048 rows x 64 uint32 words) ----------------
__global__ __launch_bounds__(256) void build_mask_k(const int* __restrict__ adj,
                                                    unsigned long long* __restrict__ mb) {
  const int row = blockIdx.x;
  const int t = threadIdx.x;
  const int wave = t >> 6;
  const int lane = t & 63;
#pragma unroll
  for (int iter = 0; iter < NN / 256; ++iter) {
    const int j = iter * 256 + t;
    const int v = adj[(size_t)row * NN + j];
    const unsigned long long m = __ballot(v > 0);
    if (lane == 0) mb[(size_t)row * 32 + iter * 4 + wave] = m;
  }
}

// ---------------- GEMM: C[p] = A[b] @ B[h], Ncols=64, 32-row tiles ----------------
// Also emits WhB: bf16 copy of C swizzled into MFMA B-fragment order:
//   element (k, n) -> WhB[p*131072 + (kb*4 + nt)*512 + (quad*16 + nl)*8 + j]
//   where kb=k/32, quad=(k%32)/8, j=k%8, nt=n/16, nl=n%16.
__global__ __launch_bounds__(256) void gemm64_k(const float* __restrict__ Aall,
                                                const float* __restrict__ Ball,
                                                float* __restrict__ Call,
                                                __bf16* __restrict__ WhBAll,
                                                int K, long aStrideB, long bStrideH,
                                                long cStrideP) {
  const int p = blockIdx.y;
  const int bb = p & 3, hh = p >> 2;
  const float* A = Aall + (long)bb * aStrideB;
  const float* Bw = Ball + (long)hh * bStrideH;
  float* C = Call + (long)p * cStrideP;
  const int r0 = blockIdx.x * 32;
  const int t = threadIdx.x;
  __shared__ float As[32][33];
  __shared__ float Bs[32][64];
  const int cg = t & 15, rb = t >> 4;  // cols cg*4..+3, rows rb and rb+16
  float acc0[4] = {0.f, 0.f, 0.f, 0.f};
  float acc1[4] = {0.f, 0.f, 0.f, 0.f};
  for (int k0 = 0; k0 < K; k0 += 32) {
#pragma unroll
    for (int q = 0; q < 4; ++q) {  // stage A 32x32
      const int idx = q * 256 + t;
      const int tr = idx >> 5, tk = idx & 31;
      As[tr][tk] = A[(long)(r0 + tr) * K + (k0 + tk)];
    }
#pragma unroll
    for (int q = 0; q < 8; ++q) {  // stage B 32x64
      const int idx = q * 256 + t;
      const int kr = idx >> 6, c = idx & 63;
      Bs[kr][c] = Bw[(long)(k0 + kr) * 64 + c];
    }
    __syncthreads();
#pragma unroll 8
    for (int k = 0; k < 32; ++k) {
      const float a0 = As[rb][k];
      const float a1 = As[rb + 16][k];
      const float4 bv = *(const float4*)&Bs[k][cg * 4];
      acc0[0] += a0 * bv.x; acc0[1] += a0 * bv.y;
      acc0[2] += a0 * bv.z; acc0[3] += a0 * bv.w;
      acc1[0] += a1 * bv.x; acc1[1] += a1 * bv.y;
      acc1[2] += a1 * bv.z; acc1[3] += a1 * bv.w;
    }
    __syncthreads();
  }
  float* c0 = C + (long)(r0 + rb) * 64 + cg * 4;
  float* c1 = C + (long)(r0 + rb + 16) * 64 + cg * 4;
#pragma unroll
  for (int q = 0; q < 4; ++q) { c0[q] = acc0[q]; c1[q] = acc1[q]; }

  // swizzled bf16 store for MFMA B-fragments (this 32-row tile is kb = blockIdx.x)
  __bf16* wb = WhBAll + (long)p * 131072 + (long)blockIdx.x * 2048;
#pragma unroll
  for (int q = 0; q < 4; ++q) {
    const int n = cg * 4 + q;
    const int nt = n >> 4, nl = n & 15;
    {
      const int kw = rb;
      wb[(nt * 64 + ((kw >> 3) << 4) + nl) * 8 + (kw & 7)] = (__bf16)acc0[q];
    }
    {
      const int kw = rb + 16;
      wb[(nt * 64 + ((kw >> 3) << 4) + nl) * 8 + (kw & 7)] = (__bf16)acc1[q];
    }
  }
}

// ---------------- esrc/edst: per-row dot(Wh_row, a_lo/a_hi) ----------------
__global__ __launch_bounds__(256) void ee_k(const float* __restrict__ WhAll,
                                            const float* __restrict__ aAll,
                                            float* __restrict__ esrc,
                                            float* __restrict__ edst,
                                            long whStride, long aStrideH) {
  const int p = blockIdx.y;
  const int hh = p >> 2;
  const float* row = WhAll + (long)p * whStride + (long)(blockIdx.x * 256 + threadIdx.x) * 64;
  const float* av = aAll + (long)hh * aStrideH;
  float s0 = 0.f, s1 = 0.f;
#pragma unroll 16
  for (int f = 0; f < 64; ++f) {
    const float w = row[f];
    s0 += w * av[f];
    s1 += w * av[64 + f];
  }
  const long n = (long)p * NN + blockIdx.x * 256 + threadIdx.x;
  esrc[n] = s0;
  edst[n] = s1;
}

// ---------------- fused masked-softmax + P@Wh via MFMA ----------------
// Block = 4 waves; each wave owns 32 rows (two 16-row M-frags), all 64 cols.
// Per k-step (32): lane builds two A-frags of P in registers, loads 4 B-frags
// (pre-swizzled bf16) from global, 8 MFMAs. No LDS, no __syncthreads.
__global__ __launch_bounds__(256) void attn_mfma_k(
    const __bf16* __restrict__ WhBAll, const float* __restrict__ esrcAll,
    const float* __restrict__ edstAll, const unsigned int* __restrict__ mb,
    float* __restrict__ outF, float* __restrict__ outB,
    int rowStride, long strideB, long strideH) {
  const int p = blockIdx.y;
  const int bb = p & 3, hh = p >> 2;
  const __bf16* WhB = WhBAll + (long)p * 131072;
  const float* esrc = esrcAll + (long)p * NN;
  const float* edst = edstAll + (long)p * NN;
  const long outOff = (long)bb * strideB + (long)hh * strideH;
  const int t = threadIdx.x;
  const int lane = t & 63;
  const int wave = t >> 6;
  const int i0 = blockIdx.x * 128 + wave * 32;
  const int quad = lane >> 4;
  const int lm = lane & 15;

  // per-wave global max of edst -> safe-softmax bound (lrelu monotone)
  float mx = -3.0e38f;
  for (int k = lane; k < NN; k += 64) mx = fmaxf(mx, edst[k]);
#pragma unroll
  for (int off = 32; off >= 1; off >>= 1) mx = fmaxf(mx, __shfl_xor(mx, off));

  const float es0 = esrc[i0 + lm];
  const float es1 = esrc[i0 + 16 + lm];
  const float pm0 = lrelu(es0 + mx);
  const float pm1 = lrelu(es1 + mx);
  const unsigned int* mrow0 = mb + (long)(i0 + lm) * 64;
  const unsigned int* mrow1 = mb + (long)(i0 + 16 + lm) * 64;

  f32x4 acc[2][4] = {};
  float lsum0 = 0.f, lsum1 = 0.f;

  for (int kb = 0; kb < 64; ++kb) {
    const float4 eda = *(const float4*)(edst + kb * 32 + quad * 8);
    const float4 edb = *(const float4*)(edst + kb * 32 + quad * 8 + 4);
    const unsigned int wq0 = mrow0[kb] >> (quad * 8);
    const unsigned int wq1 = mrow1[kb] >> (quad * 8);
    const float edv[8] = {eda.x, eda.y, eda.z, eda.w, edb.x, edb.y, edb.z, edb.w};
    bf16x8 af0, af1;
#pragma unroll
    for (int j = 0; j < 8; ++j) {
      const float p0 = ((wq0 >> j) & 1u) ? __expf(lrelu(es0 + edv[j]) - pm0) : 0.f;
      lsum0 += p0;
      af0[j] = (__bf16)p0;
      const float p1 = ((wq1 >> j) & 1u) ? __expf(lrelu(es1 + edv[j]) - pm1) : 0.f;
      lsum1 += p1;
      af1[j] = (__bf16)p1;
    }
    const bf16x8* bp = (const bf16x8*)(WhB + (long)kb * 2048);
#pragma unroll
    for (int nt = 0; nt < 4; ++nt) {
      const bf16x8 bfr = bp[nt * 64 + lane];
      acc[0][nt] = __builtin_amdgcn_mfma_f32_16x16x32_bf16(af0, bfr, acc[0][nt], 0, 0, 0);
      acc[1][nt] = __builtin_amdgcn_mfma_f32_16x16x32_bf16(af1, bfr, acc[1][nt], 0, 0, 0);
    }
  }

  // row sums: butterfly over the 4 lanes sharing each row (xor 16, 32)
  lsum0 += __shfl_xor(lsum0, 16); lsum0 += __shfl_xor(lsum0, 32);
  lsum1 += __shfl_xor(lsum1, 16); lsum1 += __shfl_xor(lsum1, 32);

  // epilogue: C/D layout col=lane&15, row=quad*4+reg (per 16x16 tile)
#pragma unroll
  for (int g = 0; g < 2; ++g) {
    const float lsg = g ? lsum1 : lsum0;
#pragma unroll
    for (int reg = 0; reg < 4; ++reg) {
      const int row = i0 + g * 16 + quad * 4 + reg;
      const float ls = __shfl(lsg, quad * 4 + reg);
      const float il = ls > 0.f ? 1.0f / ls : 0.f;
#pragma unroll
      for (int nt = 0; nt < 4; ++nt) {
        float v = acc[g][nt][reg] * il;
        v = v > 0.f ? v : expm1f(v);  // elu
        const long o = outOff + (long)row * rowStride + nt * 16 + lm;
        outF[o] = v;
        if (outB) outB[o] = v;
      }
    }
  }
}

// ---------------- layer-3 Wh3 = imgfeat @ W2 (K=64, Nc=16) ----------------
__global__ __launch_bounds__(256) void gemm16_k(const float* __restrict__ Aall,
                                                const float* __restrict__ Bw,
                                                float* __restrict__ Call) {
  const int bb = blockIdx.y;
  const float* A = Aall + (long)bb * NN * 64;
  float* C = Call + (long)bb * NN * 16;
  const int r0 = blockIdx.x * 16;
  const int t = threadIdx.x;
  __shared__ float As[16][65];
  __shared__ float Bs[64][16];
  const int c = t & 15, r = t >> 4;
#pragma unroll
  for (int q = 0; q < 4; ++q) {
    const int idx = q * 256 + t;
    As[idx >> 6][idx & 63] = A[(long)(r0 + (idx >> 6)) * 64 + (idx & 63)];
    Bs[idx >> 4][idx & 15] = Bw[idx];
  }
  __syncthreads();
  float acc = 0.f;
#pragma unroll 16
  for (int k = 0; k < 64; ++k) acc += As[r][k] * Bs[k][c];
  C[(long)(r0 + r) * 16 + c] = acc;
}

// ---------------- layer-3 finalize: only row 0 of attention is needed ----------------
__global__ __launch_bounds__(256) void layer3_k(const float* __restrict__ Wh3,
                                                const float* __restrict__ a2,
                                                const unsigned int* __restrict__ mb,
                                                float* __restrict__ outPre) {
  const int bb = blockIdx.x, t = threadIdx.x;
  const float* W = Wh3 + (long)bb * NN * 16;
  __shared__ float wmax[4];
  __shared__ float mfin;
  __shared__ float wsum[4];
  __shared__ float vacc[4][16];
  float alo[16], ahi[16];
#pragma unroll
  for (int c = 0; c < 16; ++c) { alo[c] = a2[c]; ahi[c] = a2[16 + c]; }
  float es = 0.f;
#pragma unroll
  for (int c = 0; c < 16; ++c) es += W[c] * alo[c];

  float ereg[NN / 256];
  float lmax = -3.0e38f;
  int qi = 0;
  for (int j = t; j < NN; j += 256, ++qi) {
    float ed = 0.f;
#pragma unroll
    for (int c = 0; c < 16; ++c) ed += W[(long)j * 16 + c] * ahi[c];
    float e = es + ed;
    e = e >= 0.f ? e : 0.2f * e;
    const bool ok = (mb[j >> 5] >> (j & 31)) & 1u;
    ereg[qi] = ok ? e : -3.0e38f;
    if (ok) lmax = fmaxf(lmax, e);
  }
#pragma unroll
  for (int off = 32; off > 0; off >>= 1) lmax = fmaxf(lmax, __shfl_down(lmax, off));
  if ((t & 63) == 0) wmax[t >> 6] = lmax;
  __syncthreads();
  if (t == 0) mfin = fmaxf(fmaxf(wmax[0], wmax[1]), fmaxf(wmax[2], wmax[3]));
  __syncthreads();
  const float m = mfin;

  float lsum = 0.f;
  float acc[16];
#pragma unroll
  for (int c = 0; c < 16; ++c) acc[c] = 0.f;
  qi = 0;
  for (int j = t; j < NN; j += 256, ++qi) {
    const float pv = __expf(ereg[qi] - m);  // masked -> exp(-huge) = 0
    lsum += pv;
#pragma unroll
    for (int c = 0; c < 16; ++c) acc[c] += pv * W[(long)j * 16 + c];
  }
#pragma unroll
  for (int off = 32; off > 0; off >>= 1) {
    lsum += __shfl_down(lsum, off);
#pragma unroll
    for (int c = 0; c < 16; ++c) acc[c] += __shfl_down(acc[c], off);
  }
  if ((t & 63) == 0) {
    wsum[t >> 6] = lsum;
#pragma unroll
    for (int c = 0; c < 16; ++c) vacc[t >> 6][c] = acc[c];
  }
  __syncthreads();
  if (t < 16) {
    const float a = vacc[0][t] + vacc[1][t] + vacc[2][t] + vacc[3][t];
    const float l = wsum[0] + wsum[1] + wsum[2] + wsum[3];
    float v = a / l;
    v = v > 0.f ? v : expm1f(v);
    outPre[bb * 16 + t] = v;
  }
}

// ---------------- host ----------------
extern "C" void kernel_launch(void* const* d_in, const int* in_sizes, int n_in,
                              void* d_out, int out_size, void* d_ws, size_t ws_size,
                              hipStream_t stream) {
  (void)in_sizes; (void)n_in; (void)out_size; (void)ws_size;
  constexpr int B = 4, N = NN, FIN = 128, NHID = 64, H = 8;

  const float* slices = (const float*)d_in[0];
  const int* adj = (const int*)d_in[1];
  const float* Ws = (const float*)d_in[2];
  const float* As = (const float*)d_in[3];
  const float* W1 = (const float*)d_in[4];
  const float* a1 = (const float*)d_in[5];
  const float* W2 = (const float*)d_in[6];
  const float* a2 = (const float*)d_in[7];
  float* out = (float*)d_out;

  char* w = (char*)d_ws;
  size_t off = 0;
  auto alloc = [&](size_t bytes) {
    void* p = w + off;
    off += (bytes + 255) & ~(size_t)255;
    return p;
  };
  unsigned long long* mb = (unsigned long long*)alloc((size_t)N * 32 * 8);   // 512 KB
  float* Wh1   = (float*)alloc((size_t)H * B * N * NHID * 4);                // 16 MB
  __bf16* WhB1 = (__bf16*)alloc((size_t)H * B * 131072 * 2);                 // 8 MB
  float* esrc1 = (float*)alloc((size_t)H * B * N * 4);
  float* edst1 = (float*)alloc((size_t)H * B * N * 4);
  float* x     = (float*)alloc((size_t)B * N * H * NHID * 4);                // 16 MB
  float* Wh2   = (float*)alloc((size_t)B * N * NHID * 4);                    // 2 MB
  __bf16* WhB2 = (__bf16*)alloc((size_t)B * 131072 * 2);                     // 1 MB
  float* esrc2 = (float*)alloc((size_t)B * N * 4);
  float* edst2 = (float*)alloc((size_t)B * N * 4);
  float* img   = (float*)alloc((size_t)B * N * NHID * 4);                    // 2 MB
  float* Wh3   = (float*)alloc((size_t)B * N * 16 * 4);                      // 512 KB

  const unsigned int* mb32 = (const unsigned int*)mb;

  build_mask_k<<<dim3(N), dim3(256), 0, stream>>>(adj, mb);

  // layer 1: Wh1[h*4+b] = slices[b] @ Ws[h] (+ bf16 swizzled WhB1)
  gemm64_k<<<dim3(N / 32, H * B), dim3(256), 0, stream>>>(
      slices, Ws, Wh1, WhB1, FIN, (long)N * FIN, (long)FIN * NHID, (long)N * NHID);
  ee_k<<<dim3(N / 256, H * B), dim3(256), 0, stream>>>(
      Wh1, As, esrc1, edst1, (long)N * NHID, (long)2 * NHID);
  // x[b][n][h*64+f] = elu(att @ Wh1)
  attn_mfma_k<<<dim3(N / 128, H * B), dim3(256), 0, stream>>>(
      WhB1, esrc1, edst1, mb32, x, (float*)nullptr,
      H * NHID, (long)N * H * NHID, (long)NHID);

  // layer 2: Wh2[b] = x[b] @ W1; img = elu(att @ Wh2); image_feature -> out
  gemm64_k<<<dim3(N / 32, B), dim3(256), 0, stream>>>(
      x, W1, Wh2, WhB2, H * NHID, (long)N * H * NHID, 0L, (long)N * NHID);
  ee_k<<<dim3(N / 256, B), dim3(256), 0, stream>>>(
      Wh2, a1, esrc2, edst2, (long)N * NHID, 0L);
  attn_mfma_k<<<dim3(N / 128, B), dim3(256), 0, stream>>>(
      WhB2, esrc2, edst2, mb32, img, out,
      NHID, (long)N * NHID, 0L);

  // layer 3: only attention row 0 matters for pre[:,0,:]
  gemm16_k<<<dim3(N / 16, B), dim3(256), 0, stream>>>(img, W2, Wh3);
  layer3_k<<<dim3(B), dim3(256), 0, stream>>>(Wh3, a2, mb32, out + (size_t)B * N * NHID);
}

// Round 4
// 343.214 us; speedup vs baseline: 2.0876x; 1.0112x over previous
//
#include <hip/hip_runtime.h>
#include <hip/hip_bf16.h>
#include <cstdint>

// GAT 3-layer pipeline, MI355X. B=4, N=2048, Fin=128, nhid=64, H=8, emb=64, nclass=16.
// fp32 tensors; d_out = [image_feature (4*2048*64) | pre (4*16)] fp32.
// Round 4: exp-free P-gen (p = max(E*F, G*H)), u16 mask plane AND on packed bf16,
// ones-column MFMA row sums, hi/lo-split bf16 MFMA GEMMs with fused esrc/edst epilogue.

#define NN 2048

typedef float f32x4 __attribute__((ext_vector_type(4)));
typedef __bf16 bf16x8 __attribute__((ext_vector_type(8)));

__device__ __forceinline__ unsigned pkbf(float a, float b) {
  __hip_bfloat162 t = __float22bfloat162_rn(make_float2(a, b));
  unsigned r;
  __builtin_memcpy(&r, &t, 4);
  return r;
}

// ---------------- adj -> u16 mask plane (0xFFFF / 0) ----------------
__global__ __launch_bounds__(256) void build_plane_k(const int* __restrict__ adj,
                                                     unsigned short* __restrict__ plane) {
  const int i = blockIdx.x;
#pragma unroll
  for (int jt = 0; jt < NN / 256; ++jt) {
    const int j = jt * 256 + threadIdx.x;
    plane[(long)i * NN + j] = adj[(long)i * NN + j] > 0 ? 0xFFFFu : 0u;
  }
}

// ---------------- W (fp32 [K x 64] per instance) -> bf16 hi/lo B-frag planes --------
// frag pos for (k,n): ((k>>5)*4 + (n>>4))*512 + (((k>>3)&3)*16 + (n&15))*8 + (k&7)
__global__ __launch_bounds__(256) void swizw_k(const float* __restrict__ W,
                                               __bf16* __restrict__ hi,
                                               __bf16* __restrict__ lo, int K) {
  const long inst = blockIdx.y;
  const float* w = W + inst * K * 64;
  __bf16* h = hi + inst * K * 64;
  __bf16* l = lo + inst * K * 64;
  for (int idx = blockIdx.x * 256 + threadIdx.x; idx < K * 64; idx += gridDim.x * 256) {
    const int k = idx >> 6, n = idx & 63;
    const float v = w[idx];
    const __bf16 vh = (__bf16)v;
    const __bf16 vl = (__bf16)(v - (float)vh);
    const int pos = ((k >> 5) * 4 + (n >> 4)) * 512 + (((k >> 3) & 3) * 16 + (n & 15)) * 8 + (k & 7);
    h[pos] = vh;
    l[pos] = vl;
  }
}

// ---------------- MFMA GEMM (M=2048, N=64) + fused esrc/edst/E/G/F/H + WhB frags ----
// p = blockIdx.y; A instance = p&3, W/avec instance = p>>2.
// Triple product AhBh + AlBh + AhBl => ~fp32 accuracy.
__global__ __launch_bounds__(256) void gemm_mfma_k(
    const float* __restrict__ Aall, const __bf16* __restrict__ WFhi,
    const __bf16* __restrict__ WFlo, const float* __restrict__ avecAll,
    __bf16* __restrict__ WhBAll, float* __restrict__ Eo, float* __restrict__ Go,
    float* __restrict__ Fo, float* __restrict__ Ho, int K, long aStrideB) {
  const int p = blockIdx.y;
  const float* A = Aall + (long)(p & 3) * aStrideB;
  const long wfOff = (long)(p >> 2) * K * 64;
  const __bf16* BhF = WFhi + wfOff;
  const __bf16* BlF = WFlo + wfOff;
  const float* av = avecAll + (long)(p >> 2) * 128;
  __bf16* WhB = WhBAll + (long)p * NN * 64;
  float* E = Eo + (long)p * NN;
  float* G = Go + (long)p * NN;
  float* F = Fo + (long)p * NN;
  float* Hh = Ho + (long)p * NN;

  const int t = threadIdx.x, lane = t & 63, wave = t >> 6;
  const int quad = lane >> 4, lm = lane & 15;
  const int i0w = blockIdx.x * 64 + wave * 16;
  const float* Arow = A + (long)(i0w + lm) * K;

  f32x4 acc[4];
#pragma unroll
  for (int nt = 0; nt < 4; ++nt) acc[nt] = (f32x4){0.f, 0.f, 0.f, 0.f};

  for (int k0 = 0; k0 < K; k0 += 32) {
    const float4 a0 = *(const float4*)(Arow + k0 + quad * 8);
    const float4 a1 = *(const float4*)(Arow + k0 + quad * 8 + 4);
    const float av8[8] = {a0.x, a0.y, a0.z, a0.w, a1.x, a1.y, a1.z, a1.w};
    bf16x8 ah, al;
#pragma unroll
    for (int j = 0; j < 8; ++j) {
      const __bf16 h = (__bf16)av8[j];
      ah[j] = h;
      al[j] = (__bf16)(av8[j] - (float)h);
    }
    const bf16x8* bh = (const bf16x8*)(BhF + (long)(k0 >> 5) * 2048);
    const bf16x8* bl = (const bf16x8*)(BlF + (long)(k0 >> 5) * 2048);
#pragma unroll
    for (int nt = 0; nt < 4; ++nt) {
      const bf16x8 bhf = bh[nt * 64 + lane];
      const bf16x8 blf = bl[nt * 64 + lane];
      acc[nt] = __builtin_amdgcn_mfma_f32_16x16x32_bf16(ah, bhf, acc[nt], 0, 0, 0);
      acc[nt] = __builtin_amdgcn_mfma_f32_16x16x32_bf16(al, bhf, acc[nt], 0, 0, 0);
      acc[nt] = __builtin_amdgcn_mfma_f32_16x16x32_bf16(ah, blf, acc[nt], 0, 0, 0);
    }
  }

  // fused esrc/edst: per-row dot with a_lo / a_hi, butterfly over the 16 lm lanes
  float alo[4], ahi[4];
#pragma unroll
  for (int nt = 0; nt < 4; ++nt) {
    alo[nt] = av[nt * 16 + lm];
    ahi[nt] = av[64 + nt * 16 + lm];
  }
#pragma unroll
  for (int reg = 0; reg < 4; ++reg) {
    float es = 0.f, ed = 0.f;
#pragma unroll
    for (int nt = 0; nt < 4; ++nt) {
      es += acc[nt][reg] * alo[nt];
      ed += acc[nt][reg] * ahi[nt];
    }
#pragma unroll
    for (int m = 1; m < 16; m <<= 1) {
      es += __shfl_xor(es, m);
      ed += __shfl_xor(ed, m);
    }
    if (lm == 0) {
      const int r = i0w + quad * 4 + reg;
      E[r] = __expf(es);
      G[r] = __expf(0.2f * es);
      F[r] = __expf(ed);
      Hh[r] = __expf(0.2f * ed);
    }
  }

  // WhB (attention B-frag order) bf16 stores: rows here are attention-k
  const int r0 = i0w + quad * 4;
  const long base = ((long)(r0 >> 5) * 4) * 512 + (((r0 >> 3) & 3) * 16 + lm) * 8 + (r0 & 7);
#pragma unroll
  for (int nt = 0; nt < 4; ++nt) {
    const unsigned lo32 = pkbf(acc[nt][0], acc[nt][1]);
    const unsigned hi32 = pkbf(acc[nt][2], acc[nt][3]);
    *(uint2*)(WhB + base + nt * 512) = make_uint2(lo32, hi32);
  }
}

// ---------------- attention: P = mask & max(E*F, G*H), out = elu((P@WhB)/rowsum) ----
// 4 waves/block, 32 rows/wave (2 A-frag groups), no LDS, no barriers.
__global__ __launch_bounds__(256) void attn_k(
    const __bf16* __restrict__ WhBAll, const float* __restrict__ Eb,
    const float* __restrict__ Gb, const float* __restrict__ Fb,
    const float* __restrict__ Hb, const unsigned short* __restrict__ plane,
    float* __restrict__ out1, float* __restrict__ out2, int rowStride, long strideB) {
  const int p = blockIdx.y;
  const __bf16* WhB = WhBAll + (long)p * NN * 64;
  const float* E = Eb + (long)p * NN;
  const float* G = Gb + (long)p * NN;
  const float* F = Fb + (long)p * NN;
  const float* Hv = Hb + (long)p * NN;
  const int t = threadIdx.x, lane = t & 63, wave = t >> 6;
  const int quad = lane >> 4, lm = lane & 15;
  const int i0 = blockIdx.x * 128 + wave * 32;

  const float E0 = E[i0 + lm], G0 = G[i0 + lm];
  const float E1 = E[i0 + 16 + lm], G1 = G[i0 + 16 + lm];
  const unsigned short* mp0 = plane + (long)(i0 + lm) * NN;
  const unsigned short* mp1 = plane + (long)(i0 + 16 + lm) * NN;

  bf16x8 ones;
#pragma unroll
  for (int j = 0; j < 8; ++j) ones[j] = (lm == 0) ? (__bf16)1.0f : (__bf16)0.0f;

  f32x4 acc0[4], acc1[4], sum0, sum1;
#pragma unroll
  for (int nt = 0; nt < 4; ++nt) {
    acc0[nt] = (f32x4){0.f, 0.f, 0.f, 0.f};
    acc1[nt] = (f32x4){0.f, 0.f, 0.f, 0.f};
  }
  sum0 = (f32x4){0.f, 0.f, 0.f, 0.f};
  sum1 = (f32x4){0.f, 0.f, 0.f, 0.f};

  const bf16x8* bp = (const bf16x8*)WhB;

#pragma unroll 2
  for (int kb = 0; kb < 64; ++kb) {
    const int c0 = kb * 32 + quad * 8;
    const float4 Fa = *(const float4*)(F + c0);
    const float4 Fc = *(const float4*)(F + c0 + 4);
    const float4 Ha = *(const float4*)(Hv + c0);
    const float4 Hc = *(const float4*)(Hv + c0 + 4);
    const uint4 m0 = *(const uint4*)(mp0 + c0);
    const uint4 m1 = *(const uint4*)(mp1 + c0);
    const float Fv8[8] = {Fa.x, Fa.y, Fa.z, Fa.w, Fc.x, Fc.y, Fc.z, Fc.w};
    const float Hv8[8] = {Ha.x, Ha.y, Ha.z, Ha.w, Hc.x, Hc.y, Hc.z, Hc.w};

    union { uint4 u; bf16x8 v; } A0, A1;
    A0.u.x = pkbf(fmaxf(E0 * Fv8[0], G0 * Hv8[0]), fmaxf(E0 * Fv8[1], G0 * Hv8[1])) & m0.x;
    A0.u.y = pkbf(fmaxf(E0 * Fv8[2], G0 * Hv8[2]), fmaxf(E0 * Fv8[3], G0 * Hv8[3])) & m0.y;
    A0.u.z = pkbf(fmaxf(E0 * Fv8[4], G0 * Hv8[4]), fmaxf(E0 * Fv8[5], G0 * Hv8[5])) & m0.z;
    A0.u.w = pkbf(fmaxf(E0 * Fv8[6], G0 * Hv8[6]), fmaxf(E0 * Fv8[7], G0 * Hv8[7])) & m0.w;
    A1.u.x = pkbf(fmaxf(E1 * Fv8[0], G1 * Hv8[0]), fmaxf(E1 * Fv8[1], G1 * Hv8[1])) & m1.x;
    A1.u.y = pkbf(fmaxf(E1 * Fv8[2], G1 * Hv8[2]), fmaxf(E1 * Fv8[3], G1 * Hv8[3])) & m1.y;
    A1.u.z = pkbf(fmaxf(E1 * Fv8[4], G1 * Hv8[4]), fmaxf(E1 * Fv8[5], G1 * Hv8[5])) & m1.z;
    A1.u.w = pkbf(fmaxf(E1 * Fv8[6], G1 * Hv8[6]), fmaxf(E1 * Fv8[7], G1 * Hv8[7])) & m1.w;

#pragma unroll
    for (int nt = 0; nt < 4; ++nt) {
      const bf16x8 bfr = bp[(kb * 4 + nt) * 64 + lane];
      acc0[nt] = __builtin_amdgcn_mfma_f32_16x16x32_bf16(A0.v, bfr, acc0[nt], 0, 0, 0);
      acc1[nt] = __builtin_amdgcn_mfma_f32_16x16x32_bf16(A1.v, bfr, acc1[nt], 0, 0, 0);
    }
    sum0 = __builtin_amdgcn_mfma_f32_16x16x32_bf16(A0.v, ones, sum0, 0, 0, 0);
    sum1 = __builtin_amdgcn_mfma_f32_16x16x32_bf16(A1.v, ones, sum1, 0, 0, 0);
  }

  auto epil = [&](const f32x4(&acc)[4], const f32x4& sm, int g) {
#pragma unroll
    for (int reg = 0; reg < 4; ++reg) {
      const int row = i0 + g * 16 + quad * 4 + reg;
      const float ls = __shfl(sm[reg], quad * 16);
      const float il = ls > 0.f ? 1.f / ls : 0.f;
#pragma unroll
      for (int nt = 0; nt < 4; ++nt) {
        float v = acc[nt][reg] * il;
        v = v > 0.f ? v : expm1f(v);  // elu
        const long o = (long)(p & 3) * strideB + (long)row * rowStride + (p >> 2) * 64 + nt * 16 + lm;
        out1[o] = v;
        if (out2) out2[o] = v;
      }
    }
  };
  epil(acc0, sum0, 0);
  epil(acc1, sum1, 1);
}

// ---------------- layer-3 Wh3 = imgfeat @ W2 (K=64, Nc=16), fp32 ----------------
__global__ __launch_bounds__(256) void gemm16_k(const float* __restrict__ Aall,
                                                const float* __restrict__ Bw,
                                                float* __restrict__ Call) {
  const int bb = blockIdx.y;
  const float* A = Aall + (long)bb * NN * 64;
  float* C = Call + (long)bb * NN * 16;
  const int r0 = blockIdx.x * 16;
  const int t = threadIdx.x;
  __shared__ float As[16][65];
  __shared__ float Bs[64][16];
  const int c = t & 15, r = t >> 4;
#pragma unroll
  for (int q = 0; q < 4; ++q) {
    const int idx = q * 256 + t;
    As[idx >> 6][idx & 63] = A[(long)(r0 + (idx >> 6)) * 64 + (idx & 63)];
    Bs[idx >> 4][idx & 15] = Bw[idx];
  }
  __syncthreads();
  float acc = 0.f;
#pragma unroll 16
  for (int k = 0; k < 64; ++k) acc += As[r][k] * Bs[k][c];
  C[(long)(r0 + r) * 16 + c] = acc;
}

// ---------------- layer-3 finalize: only attention row 0 matters ----------------
__global__ __launch_bounds__(256) void layer3_k(const float* __restrict__ Wh3,
                                                const float* __restrict__ a2,
                                                const unsigned short* __restrict__ plane,
                                                float* __restrict__ outPre) {
  const int bb = blockIdx.x, t = threadIdx.x;
  const float* W = Wh3 + (long)bb * NN * 16;
  __shared__ float wsum[4];
  __shared__ float vacc[4][16];
  float alo[16], ahi[16];
#pragma unroll
  for (int c = 0; c < 16; ++c) {
    alo[c] = a2[c];
    ahi[c] = a2[16 + c];
  }
  float es = 0.f;
#pragma unroll
  for (int c = 0; c < 16; ++c) es += W[c] * alo[c];

  float lsum = 0.f;
  float acc[16];
#pragma unroll
  for (int c = 0; c < 16; ++c) acc[c] = 0.f;
  for (int j = t; j < NN; j += 256) {
    float ed = 0.f;
#pragma unroll
    for (int c = 0; c < 16; ++c) ed += W[(long)j * 16 + c] * ahi[c];
    float e = es + ed;
    e = fmaxf(e, 0.2f * e);
    const float pv = plane[j] ? __expf(e) : 0.f;  // logits bounded, no max pass needed
    lsum += pv;
#pragma unroll
    for (int c = 0; c < 16; ++c) acc[c] += pv * W[(long)j * 16 + c];
  }
#pragma unroll
  for (int off = 32; off > 0; off >>= 1) {
    lsum += __shfl_down(lsum, off);
#pragma unroll
    for (int c = 0; c < 16; ++c) acc[c] += __shfl_down(acc[c], off);
  }
  if ((t & 63) == 0) {
    wsum[t >> 6] = lsum;
#pragma unroll
    for (int c = 0; c < 16; ++c) vacc[t >> 6][c] = acc[c];
  }
  __syncthreads();
  if (t < 16) {
    const float a = vacc[0][t] + vacc[1][t] + vacc[2][t] + vacc[3][t];
    const float l = wsum[0] + wsum[1] + wsum[2] + wsum[3];
    float v = a / l;
    v = v > 0.f ? v : expm1f(v);
    outPre[bb * 16 + t] = v;
  }
}

// ---------------- host ----------------
extern "C" void kernel_launch(void* const* d_in, const int* in_sizes, int n_in,
                              void* d_out, int out_size, void* d_ws, size_t ws_size,
                              hipStream_t stream) {
  (void)in_sizes; (void)n_in; (void)out_size; (void)ws_size;
  constexpr int B = 4, N = NN;

  const float* slices = (const float*)d_in[0];
  const int* adj = (const int*)d_in[1];
  const float* Ws = (const float*)d_in[2];
  const float* As = (const float*)d_in[3];
  const float* W1 = (const float*)d_in[4];
  const float* a1 = (const float*)d_in[5];
  const float* W2 = (const float*)d_in[6];
  const float* a2 = (const float*)d_in[7];
  float* out = (float*)d_out;

  char* w = (char*)d_ws;
  size_t off = 0;
  auto alloc = [&](size_t bytes) {
    void* ptr = w + off;
    off += (bytes + 255) & ~(size_t)255;
    return ptr;
  };
  unsigned short* plane = (unsigned short*)alloc((size_t)N * N * 2);  // 8 MB
  __bf16* WsFh = (__bf16*)alloc((size_t)8 * 128 * 64 * 2);
  __bf16* WsFl = (__bf16*)alloc((size_t)8 * 128 * 64 * 2);
  __bf16* W1Fh = (__bf16*)alloc((size_t)512 * 64 * 2);
  __bf16* W1Fl = (__bf16*)alloc((size_t)512 * 64 * 2);
  __bf16* WhB1 = (__bf16*)alloc((size_t)32 * N * 64 * 2);  // 8 MB
  float* E1 = (float*)alloc((size_t)32 * N * 4);
  float* G1 = (float*)alloc((size_t)32 * N * 4);
  float* F1 = (float*)alloc((size_t)32 * N * 4);
  float* H1 = (float*)alloc((size_t)32 * N * 4);
  float* x = (float*)alloc((size_t)B * N * 512 * 4);  // 16 MB
  __bf16* WhB2 = (__bf16*)alloc((size_t)B * N * 64 * 2);
  float* E2 = (float*)alloc((size_t)B * N * 4);
  float* G2 = (float*)alloc((size_t)B * N * 4);
  float* F2 = (float*)alloc((size_t)B * N * 4);
  float* H2 = (float*)alloc((size_t)B * N * 4);
  float* img = (float*)alloc((size_t)B * N * 64 * 4);  // 2 MB
  float* Wh3 = (float*)alloc((size_t)B * N * 16 * 4);

  build_plane_k<<<dim3(N), dim3(256), 0, stream>>>(adj, plane);
  swizw_k<<<dim3(32, 8), dim3(256), 0, stream>>>(Ws, WsFh, WsFl, 128);
  swizw_k<<<dim3(128, 1), dim3(256), 0, stream>>>(W1, W1Fh, W1Fl, 512);

  // layer 1
  gemm_mfma_k<<<dim3(N / 64, 32), dim3(256), 0, stream>>>(
      slices, WsFh, WsFl, As, WhB1, E1, G1, F1, H1, 128, (long)N * 128);
  attn_k<<<dim3(N / 128, 32), dim3(256), 0, stream>>>(
      WhB1, E1, G1, F1, H1, plane, x, (float*)nullptr, 512, (long)N * 512);

  // layer 2
  gemm_mfma_k<<<dim3(N / 64, 4), dim3(256), 0, stream>>>(
      x, W1Fh, W1Fl, a1, WhB2, E2, G2, F2, H2, 512, (long)N * 512);
  attn_k<<<dim3(N / 128, 4), dim3(256), 0, stream>>>(
      WhB2, E2, G2, F2, H2, plane, img, out, 64, (long)N * 64);

  // layer 3
  gemm16_k<<<dim3(N / 16, B), dim3(256), 0, stream>>>(img, W2, Wh3);
  layer3_k<<<dim3(B), dim3(256), 0, stream>>>(Wh3, a2, plane, out + (size_t)B * N * 64);
}

// Round 5
// 207.103 us; speedup vs baseline: 3.4596x; 1.6572x over previous
//
#include <hip/hip_runtime.h>
#include <hip/hip_bf16.h>
#include <cstdint>

// GAT 3-layer pipeline, MI355X. B=4, N=2048, Fin=128, nhid=64, H=8, emb=64, nclass=16.
// fp32 tensors; d_out = [image_feature (4*2048*64) | pre (4*16)] fp32.
// Round 5: ping-pong register prefetch in attn/gemm (latency was the round-4 limiter),
// layer-2 attention split 4x over j with fp32 partial accumulators + combine kernel,
// gemm blocks shrunk to 128 threads for 2-4x more blocks.

#define NN 2048

typedef float f32x4 __attribute__((ext_vector_type(4)));
typedef __bf16 bf16x8 __attribute__((ext_vector_type(8)));

__device__ __forceinline__ unsigned pkbf(float a, float b) {
  __hip_bfloat162 t = __float22bfloat162_rn(make_float2(a, b));
  unsigned r;
  __builtin_memcpy(&r, &t, 4);
  return r;
}

// ---------------- adj -> u16 mask plane (0xFFFF / 0) ----------------
__global__ __launch_bounds__(256) void build_plane_k(const int* __restrict__ adj,
                                                     unsigned short* __restrict__ plane) {
  const int i = blockIdx.x;
#pragma unroll
  for (int jt = 0; jt < NN / 256; ++jt) {
    const int j = jt * 256 + threadIdx.x;
    plane[(long)i * NN + j] = adj[(long)i * NN + j] > 0 ? 0xFFFFu : 0u;
  }
}

// ---------------- W (fp32 [K x 64] per instance) -> bf16 hi/lo B-frag planes --------
// frag pos for (k,n): ((k>>5)*4 + (n>>4))*512 + (((k>>3)&3)*16 + (n&15))*8 + (k&7)
__global__ __launch_bounds__(256) void swizw_k(const float* __restrict__ W,
                                               __bf16* __restrict__ hi,
                                               __bf16* __restrict__ lo, int K) {
  const long inst = blockIdx.y;
  const float* w = W + inst * K * 64;
  __bf16* h = hi + inst * K * 64;
  __bf16* l = lo + inst * K * 64;
  for (int idx = blockIdx.x * 256 + threadIdx.x; idx < K * 64; idx += gridDim.x * 256) {
    const int k = idx >> 6, n = idx & 63;
    const float v = w[idx];
    const __bf16 vh = (__bf16)v;
    const __bf16 vl = (__bf16)(v - (float)vh);
    const int pos = ((k >> 5) * 4 + (n >> 4)) * 512 + (((k >> 3) & 3) * 16 + (n & 15)) * 8 + (k & 7);
    h[pos] = vh;
    l[pos] = vl;
  }
}

// ---------------- MFMA GEMM (M rows, N=64) + fused esrc/edst/E/G/F/H + WhB frags ----
// 128 threads (2 waves), 32 rows/block. p = blockIdx.y; A inst = p&3, W inst = p>>2.
// Triple product AhBh + AlBh + AhBl => ~fp32 accuracy. Ping-pong prefetch over k0.
struct GemmLd {
  float4 a0, a1;
  bf16x8 bh[4], bl[4];
};

__global__ __launch_bounds__(128) void gemm_mfma_k(
    const float* __restrict__ Aall, const __bf16* __restrict__ WFhi,
    const __bf16* __restrict__ WFlo, const float* __restrict__ avecAll,
    __bf16* __restrict__ WhBAll, float* __restrict__ Eo, float* __restrict__ Go,
    float* __restrict__ Fo, float* __restrict__ Ho, int K, long aStrideB) {
  const int p = blockIdx.y;
  const float* A = Aall + (long)(p & 3) * aStrideB;
  const long wfOff = (long)(p >> 2) * K * 64;
  const bf16x8* BhF = (const bf16x8*)(WFhi + wfOff);
  const bf16x8* BlF = (const bf16x8*)(WFlo + wfOff);
  const float* av = avecAll + (long)(p >> 2) * 128;
  __bf16* WhB = WhBAll + (long)p * NN * 64;
  float* E = Eo + (long)p * NN;
  float* G = Go + (long)p * NN;
  float* F = Fo + (long)p * NN;
  float* Hh = Ho + (long)p * NN;

  const int t = threadIdx.x, lane = t & 63, wave = t >> 6;
  const int quad = lane >> 4, lm = lane & 15;
  const int i0w = blockIdx.x * 32 + wave * 16;
  const float* Arow = A + (long)(i0w + lm) * K;

  f32x4 acc[4];
#pragma unroll
  for (int nt = 0; nt < 4; ++nt) acc[nt] = (f32x4){0.f, 0.f, 0.f, 0.f};

  auto LOAD = [&](GemmLd& L, int k0) {
    L.a0 = *(const float4*)(Arow + k0 + quad * 8);
    L.a1 = *(const float4*)(Arow + k0 + quad * 8 + 4);
    const int bbase = (k0 >> 5) * 256 + lane;
#pragma unroll
    for (int nt = 0; nt < 4; ++nt) {
      L.bh[nt] = BhF[bbase + nt * 64];
      L.bl[nt] = BlF[bbase + nt * 64];
    }
  };
  auto STEP = [&](const GemmLd& L) {
    const float av8[8] = {L.a0.x, L.a0.y, L.a0.z, L.a0.w, L.a1.x, L.a1.y, L.a1.z, L.a1.w};
    bf16x8 ah, al;
#pragma unroll
    for (int j = 0; j < 8; ++j) {
      const __bf16 h = (__bf16)av8[j];
      ah[j] = h;
      al[j] = (__bf16)(av8[j] - (float)h);
    }
#pragma unroll
    for (int nt = 0; nt < 4; ++nt) {
      acc[nt] = __builtin_amdgcn_mfma_f32_16x16x32_bf16(ah, L.bh[nt], acc[nt], 0, 0, 0);
      acc[nt] = __builtin_amdgcn_mfma_f32_16x16x32_bf16(al, L.bh[nt], acc[nt], 0, 0, 0);
      acc[nt] = __builtin_amdgcn_mfma_f32_16x16x32_bf16(ah, L.bl[nt], acc[nt], 0, 0, 0);
    }
  };

  GemmLd La, Lb;
  LOAD(La, 0);
  for (int k0 = 0; k0 < K; k0 += 64) {
    LOAD(Lb, k0 + 32);
    STEP(La);
    LOAD(La, (k0 + 64 < K) ? k0 + 64 : 0);
    STEP(Lb);
  }

  // fused esrc/edst: per-row dot with a_lo / a_hi, butterfly over the 16 lm lanes
  float alo[4], ahi[4];
#pragma unroll
  for (int nt = 0; nt < 4; ++nt) {
    alo[nt] = av[nt * 16 + lm];
    ahi[nt] = av[64 + nt * 16 + lm];
  }
#pragma unroll
  for (int reg = 0; reg < 4; ++reg) {
    float es = 0.f, ed = 0.f;
#pragma unroll
    for (int nt = 0; nt < 4; ++nt) {
      es += acc[nt][reg] * alo[nt];
      ed += acc[nt][reg] * ahi[nt];
    }
#pragma unroll
    for (int m = 1; m < 16; m <<= 1) {
      es += __shfl_xor(es, m);
      ed += __shfl_xor(ed, m);
    }
    if (lm == 0) {
      const int r = i0w + quad * 4 + reg;
      E[r] = __expf(es);
      G[r] = __expf(0.2f * es);
      F[r] = __expf(ed);
      Hh[r] = __expf(0.2f * ed);
    }
  }

  // WhB (attention B-frag order) bf16 stores: rows here are attention-k
  const int r0 = i0w + quad * 4;
  const long base = ((long)(r0 >> 5) * 4) * 512 + (((r0 >> 3) & 3) * 16 + lm) * 8 + (r0 & 7);
#pragma unroll
  for (int nt = 0; nt < 4; ++nt) {
    const unsigned lo32 = pkbf(acc[nt][0], acc[nt][1]);
    const unsigned hi32 = pkbf(acc[nt][2], acc[nt][3]);
    *(uint2*)(WhB + base + nt * 512) = make_uint2(lo32, hi32);
  }
}

// ---------------- attention: P = mask & max(E*F, G*H), out = elu((P@WhB)/rowsum) ----
// 4 waves/block, 32 rows/wave. Ping-pong register prefetch; optional j-split with
// fp32 partial accumulators (partAcc/partSum) combined by combine_k.
struct AttnLd {
  float4 Fa, Fc, Ha, Hc;
  uint4 m0, m1;
  bf16x8 b[4];
};

__global__ __launch_bounds__(256) void attn_k(
    const __bf16* __restrict__ WhBAll, const float* __restrict__ Eb,
    const float* __restrict__ Gb, const float* __restrict__ Fb,
    const float* __restrict__ Hb, const unsigned short* __restrict__ plane,
    float* __restrict__ out1, float* __restrict__ out2, int rowStride, long strideB,
    int jsCount, float* __restrict__ partAcc, float* __restrict__ partSum) {
  const int p = blockIdx.z;
  const int js = blockIdx.y;
  const bf16x8* bp = (const bf16x8*)(WhBAll + (long)p * NN * 64);
  const float* E = Eb + (long)p * NN;
  const float* G = Gb + (long)p * NN;
  const float* F = Fb + (long)p * NN;
  const float* Hv = Hb + (long)p * NN;
  const int t = threadIdx.x, lane = t & 63, wave = t >> 6;
  const int quad = lane >> 4, lm = lane & 15;
  const int i0 = blockIdx.x * 128 + wave * 32;
  const int kbBeg = js * (64 / jsCount);
  const int kbEnd = kbBeg + 64 / jsCount;

  const float E0 = E[i0 + lm], G0 = G[i0 + lm];
  const float E1 = E[i0 + 16 + lm], G1 = G[i0 + 16 + lm];
  const unsigned short* mp0 = plane + (long)(i0 + lm) * NN;
  const unsigned short* mp1 = plane + (long)(i0 + 16 + lm) * NN;

  bf16x8 ones;
#pragma unroll
  for (int j = 0; j < 8; ++j) ones[j] = (lm == 0) ? (__bf16)1.0f : (__bf16)0.0f;

  f32x4 acc0[4], acc1[4], sum0, sum1;
#pragma unroll
  for (int nt = 0; nt < 4; ++nt) {
    acc0[nt] = (f32x4){0.f, 0.f, 0.f, 0.f};
    acc1[nt] = (f32x4){0.f, 0.f, 0.f, 0.f};
  }
  sum0 = (f32x4){0.f, 0.f, 0.f, 0.f};
  sum1 = (f32x4){0.f, 0.f, 0.f, 0.f};

  auto LOAD = [&](AttnLd& L, int kb) {
    const int c0 = kb * 32 + quad * 8;
    L.Fa = *(const float4*)(F + c0);
    L.Fc = *(const float4*)(F + c0 + 4);
    L.Ha = *(const float4*)(Hv + c0);
    L.Hc = *(const float4*)(Hv + c0 + 4);
    L.m0 = *(const uint4*)(mp0 + c0);
    L.m1 = *(const uint4*)(mp1 + c0);
#pragma unroll
    for (int nt = 0; nt < 4; ++nt) L.b[nt] = bp[(kb * 4 + nt) * 64 + lane];
  };
  auto STEP = [&](const AttnLd& L) {
    const float Fv8[8] = {L.Fa.x, L.Fa.y, L.Fa.z, L.Fa.w, L.Fc.x, L.Fc.y, L.Fc.z, L.Fc.w};
    const float Hv8[8] = {L.Ha.x, L.Ha.y, L.Ha.z, L.Ha.w, L.Hc.x, L.Hc.y, L.Hc.z, L.Hc.w};
    union { uint4 u; bf16x8 v; } A0, A1;
    A0.u.x = pkbf(fmaxf(E0 * Fv8[0], G0 * Hv8[0]), fmaxf(E0 * Fv8[1], G0 * Hv8[1])) & L.m0.x;
    A0.u.y = pkbf(fmaxf(E0 * Fv8[2], G0 * Hv8[2]), fmaxf(E0 * Fv8[3], G0 * Hv8[3])) & L.m0.y;
    A0.u.z = pkbf(fmaxf(E0 * Fv8[4], G0 * Hv8[4]), fmaxf(E0 * Fv8[5], G0 * Hv8[5])) & L.m0.z;
    A0.u.w = pkbf(fmaxf(E0 * Fv8[6], G0 * Hv8[6]), fmaxf(E0 * Fv8[7], G0 * Hv8[7])) & L.m0.w;
    A1.u.x = pkbf(fmaxf(E1 * Fv8[0], G1 * Hv8[0]), fmaxf(E1 * Fv8[1], G1 * Hv8[1])) & L.m1.x;
    A1.u.y = pkbf(fmaxf(E1 * Fv8[2], G1 * Hv8[2]), fmaxf(E1 * Fv8[3], G1 * Hv8[3])) & L.m1.y;
    A1.u.z = pkbf(fmaxf(E1 * Fv8[4], G1 * Hv8[4]), fmaxf(E1 * Fv8[5], G1 * Hv8[5])) & L.m1.z;
    A1.u.w = pkbf(fmaxf(E1 * Fv8[6], G1 * Hv8[6]), fmaxf(E1 * Fv8[7], G1 * Hv8[7])) & L.m1.w;
#pragma unroll
    for (int nt = 0; nt < 4; ++nt) {
      acc0[nt] = __builtin_amdgcn_mfma_f32_16x16x32_bf16(A0.v, L.b[nt], acc0[nt], 0, 0, 0);
      acc1[nt] = __builtin_amdgcn_mfma_f32_16x16x32_bf16(A1.v, L.b[nt], acc1[nt], 0, 0, 0);
    }
    sum0 = __builtin_amdgcn_mfma_f32_16x16x32_bf16(A0.v, ones, sum0, 0, 0, 0);
    sum1 = __builtin_amdgcn_mfma_f32_16x16x32_bf16(A1.v, ones, sum1, 0, 0, 0);
  };

  AttnLd La, Lb;
  LOAD(La, kbBeg);
  for (int kb = kbBeg; kb < kbEnd; kb += 2) {
    LOAD(Lb, kb + 1);
    STEP(La);
    LOAD(La, (kb + 2 < kbEnd) ? kb + 2 : kbBeg);
    STEP(Lb);
  }

  if (jsCount == 1) {
    // direct epilogue: normalize + elu + store
#pragma unroll
    for (int g = 0; g < 2; ++g) {
      const f32x4* acc = g ? acc1 : acc0;
      const f32x4 sm = g ? sum1 : sum0;
#pragma unroll
      for (int reg = 0; reg < 4; ++reg) {
        const int row = i0 + g * 16 + quad * 4 + reg;
        const float ls = __shfl(sm[reg], quad * 16);
        const float il = ls > 0.f ? 1.f / ls : 0.f;
#pragma unroll
        for (int nt = 0; nt < 4; ++nt) {
          float v = acc[nt][reg] * il;
          v = v > 0.f ? v : expm1f(v);  // elu
          const long o = (long)(p & 3) * strideB + (long)row * rowStride + (p >> 2) * 64 + nt * 16 + lm;
          out1[o] = v;
          if (out2) out2[o] = v;
        }
      }
    }
  } else {
    // partial mode: unnormalized acc + sums to workspace
    float* pAcc = partAcc + ((long)p * jsCount + js) * NN * 64;
    float* pSum = partSum + ((long)p * jsCount + js) * NN;
#pragma unroll
    for (int g = 0; g < 2; ++g) {
      const f32x4* acc = g ? acc1 : acc0;
      const f32x4 sm = g ? sum1 : sum0;
#pragma unroll
      for (int reg = 0; reg < 4; ++reg) {
        const int row = i0 + g * 16 + quad * 4 + reg;
#pragma unroll
        for (int nt = 0; nt < 4; ++nt) pAcc[(long)row * 64 + nt * 16 + lm] = acc[nt][reg];
        if (lm == 0) pSum[row] = sm[reg];
      }
    }
  }
}

// ---------------- combine j-split partials: normalize + elu + dual write ----------------
__global__ __launch_bounds__(256) void combine_k(const float* __restrict__ partAcc,
                                                 const float* __restrict__ partSum,
                                                 float* __restrict__ img,
                                                 float* __restrict__ out, int JS) {
  const long idx = (long)blockIdx.x * 256 + threadIdx.x;  // inst*NN*16
  const int cg = idx & 15;
  const int row = (int)((idx >> 4) & (NN - 1));
  const int inst = (int)(idx >> 15);
  f32x4 v = (f32x4){0.f, 0.f, 0.f, 0.f};
  float s = 0.f;
  for (int js = 0; js < JS; ++js) {
    const long b = ((long)inst * JS + js) * NN;
    v += *(const f32x4*)(partAcc + (b + row) * 64 + cg * 4);
    s += partSum[b + row];
  }
  const float il = s > 0.f ? 1.f / s : 0.f;
  f32x4 r;
#pragma unroll
  for (int q = 0; q < 4; ++q) {
    float x = v[q] * il;
    r[q] = x > 0.f ? x : expm1f(x);
  }
  const long o = ((long)inst * NN + row) * 64 + cg * 4;
  *(f32x4*)(img + o) = r;
  *(f32x4*)(out + o) = r;
}

// ---------------- layer-3 Wh3 = imgfeat @ W2 (K=64, Nc=16), fp32 ----------------
__global__ __launch_bounds__(256) void gemm16_k(const float* __restrict__ Aall,
                                                const float* __restrict__ Bw,
                                                float* __restrict__ Call) {
  const int bb = blockIdx.y;
  const float* A = Aall + (long)bb * NN * 64;
  float* C = Call + (long)bb * NN * 16;
  const int r0 = blockIdx.x * 16;
  const int t = threadIdx.x;
  __shared__ float As[16][65];
  __shared__ float Bs[64][16];
  const int c = t & 15, r = t >> 4;
#pragma unroll
  for (int q = 0; q < 4; ++q) {
    const int idx = q * 256 + t;
    As[idx >> 6][idx & 63] = A[(long)(r0 + (idx >> 6)) * 64 + (idx & 63)];
    Bs[idx >> 4][idx & 15] = Bw[idx];
  }
  __syncthreads();
  float acc = 0.f;
#pragma unroll 16
  for (int k = 0; k < 64; ++k) acc += As[r][k] * Bs[k][c];
  C[(long)(r0 + r) * 16 + c] = acc;
}

// ---------------- layer-3 finalize: only attention row 0 matters ----------------
__global__ __launch_bounds__(256) void layer3_k(const float* __restrict__ Wh3,
                                                const float* __restrict__ a2,
                                                const unsigned short* __restrict__ plane,
                                                float* __restrict__ outPre) {
  const int bb = blockIdx.x, t = threadIdx.x;
  const float* W = Wh3 + (long)bb * NN * 16;
  __shared__ float wsum[4];
  __shared__ float vacc[4][16];
  float alo[16], ahi[16];
#pragma unroll
  for (int c = 0; c < 16; ++c) {
    alo[c] = a2[c];
    ahi[c] = a2[16 + c];
  }
  float es = 0.f;
#pragma unroll
  for (int c = 0; c < 16; ++c) es += W[c] * alo[c];

  float lsum = 0.f;
  float acc[16];
#pragma unroll
  for (int c = 0; c < 16; ++c) acc[c] = 0.f;
  for (int j = t; j < NN; j += 256) {
    float ed = 0.f;
#pragma unroll
    for (int c = 0; c < 16; ++c) ed += W[(long)j * 16 + c] * ahi[c];
    float e = es + ed;
    e = fmaxf(e, 0.2f * e);
    const float pv = plane[j] ? __expf(e) : 0.f;  // logits bounded, no max pass needed
    lsum += pv;
#pragma unroll
    for (int c = 0; c < 16; ++c) acc[c] += pv * W[(long)j * 16 + c];
  }
#pragma unroll
  for (int off = 32; off > 0; off >>= 1) {
    lsum += __shfl_down(lsum, off);
#pragma unroll
    for (int c = 0; c < 16; ++c) acc[c] += __shfl_down(acc[c], off);
  }
  if ((t & 63) == 0) {
    wsum[t >> 6] = lsum;
#pragma unroll
    for (int c = 0; c < 16; ++c) vacc[t >> 6][c] = acc[c];
  }
  __syncthreads();
  if (t < 16) {
    const float a = vacc[0][t] + vacc[1][t] + vacc[2][t] + vacc[3][t];
    const float l = wsum[0] + wsum[1] + wsum[2] + wsum[3];
    float v = a / l;
    v = v > 0.f ? v : expm1f(v);
    outPre[bb * 16 + t] = v;
  }
}

// ---------------- host ----------------
extern "C" void kernel_launch(void* const* d_in, const int* in_sizes, int n_in,
                              void* d_out, int out_size, void* d_ws, size_t ws_size,
                              hipStream_t stream) {
  (void)in_sizes; (void)n_in; (void)out_size; (void)ws_size;
  constexpr int B = 4, N = NN, JS2 = 4;

  const float* slices = (const float*)d_in[0];
  const int* adj = (const int*)d_in[1];
  const float* Ws = (const float*)d_in[2];
  const float* As = (const float*)d_in[3];
  const float* W1 = (const float*)d_in[4];
  const float* a1 = (const float*)d_in[5];
  const float* W2 = (const float*)d_in[6];
  const float* a2 = (const float*)d_in[7];
  float* out = (float*)d_out;

  char* w = (char*)d_ws;
  size_t off = 0;
  auto alloc = [&](size_t bytes) {
    void* ptr = w + off;
    off += (bytes + 255) & ~(size_t)255;
    return ptr;
  };
  unsigned short* plane = (unsigned short*)alloc((size_t)N * N * 2);  // 8 MB
  __bf16* WsFh = (__bf16*)alloc((size_t)8 * 128 * 64 * 2);
  __bf16* WsFl = (__bf16*)alloc((size_t)8 * 128 * 64 * 2);
  __bf16* W1Fh = (__bf16*)alloc((size_t)512 * 64 * 2);
  __bf16* W1Fl = (__bf16*)alloc((size_t)512 * 64 * 2);
  __bf16* WhB1 = (__bf16*)alloc((size_t)32 * N * 64 * 2);  // 8 MB
  float* E1 = (float*)alloc((size_t)32 * N * 4);
  float* G1 = (float*)alloc((size_t)32 * N * 4);
  float* F1 = (float*)alloc((size_t)32 * N * 4);
  float* H1 = (float*)alloc((size_t)32 * N * 4);
  float* x = (float*)alloc((size_t)B * N * 512 * 4);  // 16 MB
  __bf16* WhB2 = (__bf16*)alloc((size_t)B * N * 64 * 2);
  float* E2 = (float*)alloc((size_t)B * N * 4);
  float* G2 = (float*)alloc((size_t)B * N * 4);
  float* F2 = (float*)alloc((size_t)B * N * 4);
  float* H2 = (float*)alloc((size_t)B * N * 4);
  float* img = (float*)alloc((size_t)B * N * 64 * 4);  // 2 MB
  float* Wh3 = (float*)alloc((size_t)B * N * 16 * 4);
  float* pAcc2 = (float*)alloc((size_t)B * JS2 * N * 64 * 4);  // 8 MB
  float* pSum2 = (float*)alloc((size_t)B * JS2 * N * 4);

  build_plane_k<<<dim3(N), dim3(256), 0, stream>>>(adj, plane);
  swizw_k<<<dim3(32, 8), dim3(256), 0, stream>>>(Ws, WsFh, WsFl, 128);
  swizw_k<<<dim3(128, 1), dim3(256), 0, stream>>>(W1, W1Fh, W1Fl, 512);

  // layer 1
  gemm_mfma_k<<<dim3(N / 32, 32), dim3(128), 0, stream>>>(
      slices, WsFh, WsFl, As, WhB1, E1, G1, F1, H1, 128, (long)N * 128);
  attn_k<<<dim3(N / 128, 1, 32), dim3(256), 0, stream>>>(
      WhB1, E1, G1, F1, H1, plane, x, (float*)nullptr, 512, (long)N * 512,
      1, (float*)nullptr, (float*)nullptr);

  // layer 2 (j-split x4 + combine)
  gemm_mfma_k<<<dim3(N / 32, 4), dim3(128), 0, stream>>>(
      x, W1Fh, W1Fl, a1, WhB2, E2, G2, F2, H2, 512, (long)N * 512);
  attn_k<<<dim3(N / 128, JS2, 4), dim3(256), 0, stream>>>(
      WhB2, E2, G2, F2, H2, plane, (float*)nullptr, (float*)nullptr, 64, (long)N * 64,
      JS2, pAcc2, pSum2);
  combine_k<<<dim3(B * N * 16 / 256), dim3(256), 0, stream>>>(pAcc2, pSum2, img, out, JS2);

  // layer 3
  gemm16_k<<<dim3(N / 16, B), dim3(256), 0, stream>>>(img, W2, Wh3);
  layer3_k<<<dim3(B), dim3(256), 0, stream>>>(Wh3, a2, plane, out + (size_t)B * N * 64);
}